// Round 1
// baseline (510.032 us; speedup 1.0000x reference)
//
#include <hip/hip_runtime.h>
#include <math.h>

// CenterLoss on MI355X.
// out[0] = mean(||x_i - centers[label_i]||)/2 ; out[1..] = updated centers [1000][256].
// Strategy: counting-sort rows by label (hist -> scan -> scatter), then one
// gather pass per class that reads x exactly once and computes BOTH the loss
// contribution and the per-class column sums with no hot-path atomics.

#define D 256
#define NTHREADS 256

// labels may arrive as int32 or as int64 (low word little-endian). flag64=1 => int64.
__device__ __forceinline__ int get_label(const int* __restrict__ lraw, int i, int f64) {
    return f64 ? lraw[(size_t)2 * i] : lraw[i];
}

// Zero counters/loss, detect label word width.
__global__ __launch_bounds__(1024) void init_kernel(const int* __restrict__ lraw, int n,
                                                    int* __restrict__ counts,
                                                    int* __restrict__ flag,
                                                    double* __restrict__ lossacc) {
    __shared__ int s_or;
    const int t = threadIdx.x;
    if (t == 0) { s_or = 0; *lossacc = 0.0; }
    counts[t] = 0;
    __syncthreads();
    // Probe "high words": if labels are int64 (values < 2^31), every odd word is 0.
    int v = 0;
    #pragma unroll
    for (int k = 0; k < 4; ++k) {
        int j = t * 4 + k;              // candidate label index
        if (2 * j + 1 < n) v |= lraw[2 * j + 1];   // bound safe under int32 interp
    }
    if (v) atomicOr(&s_or, 1);
    __syncthreads();
    if (t == 0) *flag = (s_or == 0) ? 1 : 0;       // all-zero high words => int64
}

__global__ __launch_bounds__(NTHREADS) void hist_kernel(const int* __restrict__ lraw, int n,
                                                        const int* __restrict__ flag,
                                                        int* __restrict__ counts) {
    const int i = blockIdx.x * NTHREADS + threadIdx.x;
    if (i < n) atomicAdd(&counts[get_label(lraw, i, *flag)], 1);
}

// 1024-wide Hillis-Steele exclusive scan (C<=1024 classes).
__global__ __launch_bounds__(1024) void scan_kernel(const int* __restrict__ counts,
                                                    int* __restrict__ offsets,
                                                    int* __restrict__ fill) {
    __shared__ int s[1024];
    const int t = threadIdx.x;
    const int v = counts[t];
    s[t] = v;
    __syncthreads();
    for (int off = 1; off < 1024; off <<= 1) {
        int add = (t >= off) ? s[t - off] : 0;
        __syncthreads();
        s[t] += add;
        __syncthreads();
    }
    const int excl = s[t] - v;
    offsets[t] = excl;
    fill[t] = excl;
}

__global__ __launch_bounds__(NTHREADS) void scatter_kernel(const int* __restrict__ lraw, int n,
                                                           const int* __restrict__ flag,
                                                           int* __restrict__ fill,
                                                           int* __restrict__ rowidx) {
    const int i = blockIdx.x * NTHREADS + threadIdx.x;
    if (i < n) {
        const int lbl = get_label(lraw, i, *flag);
        const int pos = atomicAdd(&fill[lbl], 1);
        rowidx[pos] = i;
    }
}

// One block per class. 4 waves; each wave streams whole 1KB rows (float4/lane),
// 4-deep unrolled so 4 KB/wave is in flight to hide HBM latency.
__global__ __launch_bounds__(NTHREADS) void main_kernel(
        const float* __restrict__ x, const float* __restrict__ centers,
        const int* __restrict__ offsets, const int* __restrict__ counts,
        const int* __restrict__ rowidx, double* __restrict__ lossacc,
        float* __restrict__ out) {
    const int c = blockIdx.x;
    const int tid = threadIdx.x;
    const int wave = tid >> 6;
    const int lane = tid & 63;

    __shared__ float s_sum[4][D];
    __shared__ float s_loss[4];

    const float4 ctr = ((const float4*)(centers + (size_t)c * D))[lane];
    const int start = offsets[c];
    const int cnt = counts[c];

    float4 sum = make_float4(0.f, 0.f, 0.f, 0.f);
    float lsum = 0.f;   // identical across lanes of the wave (post-reduce)

    constexpr int U = 4;
    for (int base = wave * U; base < cnt; base += 4 * U) {
        const int nv = min(U, cnt - base);   // wave-uniform
        float4 v[U];
        #pragma unroll
        for (int k = 0; k < U; ++k) {
            if (k < nv) {
                const int r = rowidx[start + base + k];
                v[k] = ((const float4*)(x + (size_t)r * D))[lane];
            }
        }
        #pragma unroll
        for (int k = 0; k < U; ++k) {
            if (k < nv) {
                sum.x += v[k].x; sum.y += v[k].y; sum.z += v[k].z; sum.w += v[k].w;
                const float dx = v[k].x - ctr.x, dy = v[k].y - ctr.y;
                const float dz = v[k].z - ctr.z, dw = v[k].w - ctr.w;
                float sq = dx * dx + dy * dy + dz * dz + dw * dw;
                #pragma unroll
                for (int off = 32; off; off >>= 1) sq += __shfl_xor(sq, off, 64);
                lsum += sqrtf(sq);           // same value on all 64 lanes
            }
        }
    }

    ((float4*)&s_sum[wave][lane * 4])[0] = sum;
    if (lane == 0) s_loss[wave] = lsum;
    __syncthreads();

    const float tot = s_sum[0][tid] + s_sum[1][tid] + s_sum[2][tid] + s_sum[3][tid];
    const float cs = centers[(size_t)c * D + tid];
    float newc = cs;
    if (cnt > 0) {
        const float mean = tot / (float)cnt;
        newc = cs + 0.5f * (mean - cs);      // ALPHA = 0.5
    }
    out[1 + (size_t)c * D + tid] = newc;

    if (tid == 0) {
        const float bl = s_loss[0] + s_loss[1] + s_loss[2] + s_loss[3];
        atomicAdd(lossacc, (double)bl);
    }
}

__global__ void finalize_kernel(const double* __restrict__ lossacc, int n,
                                float* __restrict__ out) {
    out[0] = (float)(*lossacc / (double)n * 0.5);
}

extern "C" void kernel_launch(void* const* d_in, const int* in_sizes, int n_in,
                              void* d_out, int out_size, void* d_ws, size_t ws_size,
                              hipStream_t stream) {
    const float* x       = (const float*)d_in[0];
    const int*   lraw    = (const int*)d_in[1];
    const float* centers = (const float*)d_in[2];
    float* out = (float*)d_out;

    const int n = in_sizes[1];            // 262144 rows
    const int C = in_sizes[2] / D;        // 1000 classes

    // workspace layout (byte offsets)
    char* ws = (char*)d_ws;
    int*    counts  = (int*)(ws + 0);       // 1024 ints
    int*    offsets = (int*)(ws + 4096);    // 1024 ints
    int*    fill    = (int*)(ws + 8192);    // 1024 ints
    int*    flag    = (int*)(ws + 12288);   // 1 int
    double* lossacc = (double*)(ws + 12296);// 8-aligned
    int*    rowidx  = (int*)(ws + 16384);   // n ints

    const int nb = (n + NTHREADS - 1) / NTHREADS;

    hipLaunchKernelGGL(init_kernel, dim3(1), dim3(1024), 0, stream,
                       lraw, n, counts, flag, lossacc);
    hipLaunchKernelGGL(hist_kernel, dim3(nb), dim3(NTHREADS), 0, stream,
                       lraw, n, flag, counts);
    hipLaunchKernelGGL(scan_kernel, dim3(1), dim3(1024), 0, stream,
                       counts, offsets, fill);
    hipLaunchKernelGGL(scatter_kernel, dim3(nb), dim3(NTHREADS), 0, stream,
                       lraw, n, flag, fill, rowidx);
    hipLaunchKernelGGL(main_kernel, dim3(C), dim3(NTHREADS), 0, stream,
                       x, centers, offsets, counts, rowidx, lossacc, out);
    hipLaunchKernelGGL(finalize_kernel, dim3(1), dim3(1), 0, stream,
                       lossacc, n, out);
}

// Round 2
// 439.411 us; speedup vs baseline: 1.1607x; 1.1607x over previous
//
#include <hip/hip_runtime.h>
#include <math.h>

// CenterLoss on MI355X (gfx950).
// out[0] = mean(||x_i - centers[label_i]||)/2 ; out[1..] = updated centers [1000][256].
//
// 3 launches:
//   init_kernel   : zero counters / barriers / loss accumulator (ws is 0xAA-poisoned)
//   setup_kernel  : fused hist -> scan -> scatter (counting sort of row indices by label)
//                   64 co-resident blocks + software grid barrier; LDS-privatized
//                   histogram (global atomic chain depth 64, scatter uses LDS atomics only)
//   main_kernel   : one block per class; streams its row list (1 KB rows, float4/lane,
//                   double-buffered 4-deep so 4 KB/wave is in flight), computes loss
//                   (wave shfl-reduce + sqrt) and column sums in registers. Last block
//                   finalizes out[0] via a done-counter. x is read exactly once.

#define D 256
#define SETUP_BLOCKS 64
#define SETUP_THREADS 1024
#define MAIN_THREADS 256

// ---- software grid barrier (all SETUP_BLOCKS co-resident: 64 blocks << 256 CUs) ----
__device__ __forceinline__ void grid_barrier(int* bar) {
    __syncthreads();
    if (threadIdx.x == 0) {
        __threadfence();                       // agent-scope release of prior writes
        atomicAdd(bar, 1);                     // device-scope
        while (__hip_atomic_load(bar, __ATOMIC_ACQUIRE, __HIP_MEMORY_SCOPE_AGENT)
               < SETUP_BLOCKS) {
            __builtin_amdgcn_s_sleep(2);
        }
    }
    __syncthreads();
}

__global__ __launch_bounds__(1024) void init_kernel(int* __restrict__ counts,
                                                    int* __restrict__ bars,
                                                    double* __restrict__ lossacc) {
    counts[threadIdx.x] = 0;                   // 1024 class counters (C<=1024)
    if (threadIdx.x < 3) bars[threadIdx.x] = 0; // bar0, bar1, done
    if (threadIdx.x == 0) *lossacc = 0.0;
}

// Fused counting sort. Row partition per block is identical in phase 1 and phase 3,
// so per-block per-bin output ranges are disjoint by construction.
__global__ __launch_bounds__(SETUP_THREADS) void setup_kernel(
        const int* __restrict__ lraw, int n,
        int* __restrict__ counts, int* __restrict__ offsets,
        int* __restrict__ bar0, int* __restrict__ bar1,
        int* __restrict__ hist_all, int* __restrict__ rowidx) {
    __shared__ int sh[1024];
    __shared__ int s_flag;
    const int tid = threadIdx.x;
    const int b = blockIdx.x;

    // label word-width probe: int64 labels (<2^31) have all-zero odd words
    if (tid == 0) s_flag = 0;
    sh[tid] = 0;
    __syncthreads();
    if (tid < 512 && 2 * tid + 1 < n) {
        if (lraw[2 * tid + 1]) atomicOr(&s_flag, 1);
    }
    __syncthreads();
    const int f64 = (s_flag == 0) ? 1 : 0;

    // ---- phase 1: LDS-privatized histogram over this block's rows ----
    for (int i = b * SETUP_THREADS + tid; i < n; i += SETUP_BLOCKS * SETUP_THREADS) {
        const int lbl = f64 ? lraw[2 * (size_t)i] : lraw[i];
        atomicAdd(&sh[lbl], 1);
    }
    __syncthreads();
    const int myh = sh[tid];
    hist_all[b * 1024 + tid] = myh;            // persist per-block hist
    if (myh) atomicAdd(&counts[tid], myh);     // chain depth <= SETUP_BLOCKS

    grid_barrier(bar0);

    // ---- phase 2: block 0 exclusive-scans counts -> offsets ----
    if (b == 0) {
        const int v = counts[tid];
        sh[tid] = v;
        __syncthreads();
        for (int off = 1; off < 1024; off <<= 1) {
            const int add = (tid >= off) ? sh[tid - off] : 0;
            __syncthreads();
            sh[tid] += add;
            __syncthreads();
        }
        offsets[tid] = sh[tid] - v;
    }

    grid_barrier(bar1);

    // ---- phase 3: per-block base per bin, then scatter with LDS fetch-adds ----
    int base = offsets[tid];
    for (int pb = 0; pb < b; ++pb) base += hist_all[pb * 1024 + tid];
    __syncthreads();                            // everyone done with old sh contents
    sh[tid] = base;
    __syncthreads();
    for (int i = b * SETUP_THREADS + tid; i < n; i += SETUP_BLOCKS * SETUP_THREADS) {
        const int lbl = f64 ? lraw[2 * (size_t)i] : lraw[i];
        const int pos = atomicAdd(&sh[lbl], 1); // LDS atomic only
        rowidx[pos] = i;
    }
}

// One block per class; 4 waves; each wave owns whole rows. Double-buffered
// register staging: batch B's loads are issued before batch A is processed.
__global__ __launch_bounds__(MAIN_THREADS) void main_kernel(
        const float* __restrict__ x, const float* __restrict__ centers,
        const int* __restrict__ offsets, const int* __restrict__ counts,
        const int* __restrict__ rowidx, double* __restrict__ lossacc,
        int* __restrict__ done, int n_rows, int n_classes,
        float* __restrict__ out) {
    const int c = blockIdx.x;
    const int tid = threadIdx.x;
    const int wave = tid >> 6;
    const int lane = tid & 63;

    __shared__ float s_sum[4][D];
    __shared__ float s_loss[4];

    const float4 ctr = ((const float4*)(centers + (size_t)c * D))[lane];
    const int start = offsets[c];
    const int cnt = counts[c];

    float4 sum = make_float4(0.f, 0.f, 0.f, 0.f);
    float lsum = 0.f;

    constexpr int U = 4;            // rows per batch per wave
    constexpr int WSTR = 4 * U;     // 4 waves advance together

    float4 A[U], B[U];
    int nA = 0, nB = 0;

    auto LOAD = [&](int bs, float4* buf) -> int {
        int nv = cnt - bs;
        nv = nv > U ? U : (nv < 0 ? 0 : nv);
        #pragma unroll
        for (int k = 0; k < U; ++k) {
            if (k < nv) {
                const int r = rowidx[start + bs + k];       // wave-uniform broadcast
                buf[k] = ((const float4*)(x + (size_t)r * D))[lane];
            }
        }
        return nv;
    };
    auto PROC = [&](const float4* buf, int nv) {
        #pragma unroll
        for (int k = 0; k < U; ++k) {
            if (k < nv) {
                const float4 v = buf[k];
                sum.x += v.x; sum.y += v.y; sum.z += v.z; sum.w += v.w;
                const float dx = v.x - ctr.x, dy = v.y - ctr.y;
                const float dz = v.z - ctr.z, dw = v.w - ctr.w;
                float sq = dx * dx + dy * dy + dz * dz + dw * dw;
                #pragma unroll
                for (int o = 32; o; o >>= 1) sq += __shfl_xor(sq, o, 64);
                lsum += sqrtf(sq);              // same on all 64 lanes
            }
        }
    };

    int bs = wave * U;
    nA = LOAD(bs, A); bs += WSTR;
    while (nA) {
        nB = LOAD(bs, B); bs += WSTR;   // prefetch next batch
        PROC(A, nA);
        if (!nB) break;
        nA = LOAD(bs, A); bs += WSTR;   // prefetch following batch
        PROC(B, nB);
    }

    ((float4*)&s_sum[wave][lane * 4])[0] = sum;
    if (lane == 0) s_loss[wave] = lsum;
    __syncthreads();

    const float tot = s_sum[0][tid] + s_sum[1][tid] + s_sum[2][tid] + s_sum[3][tid];
    const float cs = centers[(size_t)c * D + tid];
    float newc = cs;
    if (cnt > 0) {
        const float mean = tot / (float)cnt;
        newc = cs + 0.5f * (mean - cs);          // ALPHA = 0.5
    }
    out[1 + (size_t)c * D + tid] = newc;

    if (tid == 0) {
        const double bl = (double)(s_loss[0] + s_loss[1] + s_loss[2] + s_loss[3]);
        atomicAdd(lossacc, bl);
        __threadfence();
        const int old = atomicAdd(done, 1);
        if (old == n_classes - 1) {              // last block finalizes
            const double L = atomicAdd(lossacc, 0.0);  // coherent read
            out[0] = (float)(L / (double)n_rows * 0.5);
        }
    }
}

extern "C" void kernel_launch(void* const* d_in, const int* in_sizes, int n_in,
                              void* d_out, int out_size, void* d_ws, size_t ws_size,
                              hipStream_t stream) {
    const float* x       = (const float*)d_in[0];
    const int*   lraw    = (const int*)d_in[1];
    const float* centers = (const float*)d_in[2];
    float* out = (float*)d_out;

    const int n = in_sizes[1];            // 262144 rows
    const int C = in_sizes[2] / D;        // 1000 classes

    // workspace layout (byte offsets into 0xAA-poisoned d_ws)
    char* ws = (char*)d_ws;
    int*    counts   = (int*)(ws + 0);        // 1024 ints
    int*    offsets  = (int*)(ws + 4096);     // 1024 ints
    int*    bars     = (int*)(ws + 8192);     // bar0, bar1, done
    double* lossacc  = (double*)(ws + 8208);  // 8-aligned
    int*    hist_all = (int*)(ws + 16384);    // SETUP_BLOCKS*1024 ints (256 KB)
    int*    rowidx   = (int*)(ws + 524288);   // n ints (1 MB)

    hipLaunchKernelGGL(init_kernel, dim3(1), dim3(1024), 0, stream,
                       counts, bars, lossacc);
    hipLaunchKernelGGL(setup_kernel, dim3(SETUP_BLOCKS), dim3(SETUP_THREADS), 0, stream,
                       lraw, n, counts, offsets, &bars[0], &bars[1], hist_all, rowidx);
    hipLaunchKernelGGL(main_kernel, dim3(C), dim3(MAIN_THREADS), 0, stream,
                       x, centers, offsets, counts, rowidx, lossacc, &bars[2], n, C, out);
}

// Round 3
// 421.231 us; speedup vs baseline: 1.2108x; 1.0432x over previous
//
#include <hip/hip_runtime.h>
#include <math.h>

// CenterLoss on MI355X (gfx950).
// out[0] = mean(||x_i - centers[label_i]||)/2 ; out[1..] = updated centers [1000][256].
//
// 4 launches:
//   init_kernel     : zero accum/counters/barriers/lossacc (ws is 0xAA-poisoned)
//   setup_kernel    : fused hist -> scan -> scatter counting sort (64 co-resident
//                     blocks + software grid barrier, LDS-privatized histogram)
//   main_kernel     : 2 blocks per class, each streams half the class's sorted rows.
//                     Row indices are pre-loaded to registers and broadcast via shfl
//                     (NO vmem on the index path -> x gathers stay 8-16KB/wave in
//                     flight under the compiler's counted vmcnt). Computes loss +
//                     column sums; merges via f32/f64 atomics.
//   finalize_kernel : centers update from accum/counts; writes out[0].

#define D 256
#define SETUP_BLOCKS 64
#define SETUP_THREADS 1024
#define MAIN_THREADS 256
#define CH 128                 // rows per chunk
#define CPB 2                  // chunks (blocks) per class

// ---- software grid barrier (SETUP_BLOCKS co-resident: 64 blocks << 256 CUs) ----
__device__ __forceinline__ void grid_barrier(int* bar) {
    __syncthreads();
    if (threadIdx.x == 0) {
        __threadfence();
        atomicAdd(bar, 1);
        while (__hip_atomic_load(bar, __ATOMIC_ACQUIRE, __HIP_MEMORY_SCOPE_AGENT)
               < SETUP_BLOCKS) {
            __builtin_amdgcn_s_sleep(2);
        }
    }
    __syncthreads();
}

__global__ __launch_bounds__(256) void init_kernel(float* __restrict__ accum,
                                                   int* __restrict__ counts,
                                                   int* __restrict__ bars,
                                                   double* __restrict__ lossacc) {
    float4* a4 = (float4*)accum;                       // 1000*256 floats = 64000 f4
    for (int i = blockIdx.x * 256 + threadIdx.x; i < 64000; i += gridDim.x * 256)
        a4[i] = make_float4(0.f, 0.f, 0.f, 0.f);
    if (blockIdx.x == 0) {
        for (int i = threadIdx.x; i < 1024; i += 256) counts[i] = 0;
        if (threadIdx.x < 3) bars[threadIdx.x] = 0;
        if (threadIdx.x == 0) *lossacc = 0.0;
    }
}

// Fused counting sort (unchanged from round 2 — verified correct).
__global__ __launch_bounds__(SETUP_THREADS) void setup_kernel(
        const int* __restrict__ lraw, int n,
        int* __restrict__ counts, int* __restrict__ offsets,
        int* __restrict__ bar0, int* __restrict__ bar1,
        int* __restrict__ hist_all, int* __restrict__ rowidx) {
    __shared__ int sh[1024];
    __shared__ int s_flag;
    const int tid = threadIdx.x;
    const int b = blockIdx.x;

    if (tid == 0) s_flag = 0;
    sh[tid] = 0;
    __syncthreads();
    if (tid < 512 && 2 * tid + 1 < n) {
        if (lraw[2 * tid + 1]) atomicOr(&s_flag, 1);
    }
    __syncthreads();
    const int f64 = (s_flag == 0) ? 1 : 0;

    for (int i = b * SETUP_THREADS + tid; i < n; i += SETUP_BLOCKS * SETUP_THREADS) {
        const int lbl = f64 ? lraw[2 * (size_t)i] : lraw[i];
        atomicAdd(&sh[lbl], 1);
    }
    __syncthreads();
    const int myh = sh[tid];
    hist_all[b * 1024 + tid] = myh;
    if (myh) atomicAdd(&counts[tid], myh);

    grid_barrier(bar0);

    if (b == 0) {
        const int v = counts[tid];
        sh[tid] = v;
        __syncthreads();
        for (int off = 1; off < 1024; off <<= 1) {
            const int add = (tid >= off) ? sh[tid - off] : 0;
            __syncthreads();
            sh[tid] += add;
            __syncthreads();
        }
        offsets[tid] = sh[tid] - v;
    }

    grid_barrier(bar1);

    int base = offsets[tid];
    for (int pb = 0; pb < b; ++pb) base += hist_all[pb * 1024 + tid];
    __syncthreads();
    sh[tid] = base;
    __syncthreads();
    for (int i = b * SETUP_THREADS + tid; i < n; i += SETUP_BLOCKS * SETUP_THREADS) {
        const int lbl = f64 ? lraw[2 * (size_t)i] : lraw[i];
        const int pos = atomicAdd(&sh[lbl], 1);
        rowidx[pos] = i;
    }
}

// 2 blocks per class; 4 waves; rows interleaved stride-4 across waves.
// Index path is vmem-free (register idx + shfl broadcast) so the 8-row batches'
// x gathers pipeline under counted vmcnt.
__global__ __launch_bounds__(MAIN_THREADS) void main_kernel(
        const float* __restrict__ x, const float* __restrict__ centers,
        const int* __restrict__ offsets, const int* __restrict__ counts,
        const int* __restrict__ rowidx,
        float* __restrict__ accum, double* __restrict__ lossacc) {
    const int c = blockIdx.x / CPB;
    const int p = blockIdx.x % CPB;
    const int tid = threadIdx.x;
    const int wave = tid >> 6;
    const int lane = tid & 63;

    __shared__ float s_sum[4][D];
    __shared__ float s_loss[4];

    const float4 ctr = ((const float4*)(centers + (size_t)c * D))[lane];
    const int start = offsets[c];
    const int cnt = counts[c];

    float4 sum = make_float4(0.f, 0.f, 0.f, 0.f);
    float lsum = 0.f;

    for (int cb = p * CH; cb < cnt; cb += CPB * CH) {
        const int len = min(CH, cnt - cb);
        const int lo = start + cb;
        // chunk's row indices -> registers (one coalesced load, no further vmem)
        const int i0 = (lane < len) ? rowidx[lo + lane] : 0;
        const int i1 = (64 + lane < len) ? rowidx[lo + 64 + lane] : 0;
        const int nw = (len > wave) ? ((len - wave + 3) >> 2) : 0;  // my row count

        constexpr int U = 8;
        float4 A[U], B[U];

        auto LOADB = [&](int bb, float4* buf) -> int {
            int nv = nw - bb * U;
            nv = nv < 0 ? 0 : (nv > U ? U : nv);
            #pragma unroll
            for (int k = 0; k < U; ++k) {
                if (k < nv) {
                    const int pos = wave + 4 * (bb * U + k);      // wave-uniform
                    const int r = __shfl(pos < 64 ? i0 : i1, pos & 63, 64);
                    buf[k] = ((const float4*)(x + (size_t)r * D))[lane];
                }
            }
            return nv;
        };
        auto PROC = [&](const float4* buf, int nv) {
            #pragma unroll
            for (int k = 0; k < U; ++k) {
                if (k < nv) {
                    const float4 v = buf[k];
                    sum.x += v.x; sum.y += v.y; sum.z += v.z; sum.w += v.w;
                    const float dx = v.x - ctr.x, dy = v.y - ctr.y;
                    const float dz = v.z - ctr.z, dw = v.w - ctr.w;
                    float sq = dx * dx + dy * dy + dz * dz + dw * dw;
                    #pragma unroll
                    for (int o = 32; o; o >>= 1) sq += __shfl_xor(sq, o, 64);
                    lsum += sqrtf(sq);               // identical on all 64 lanes
                }
            }
        };

        int bb = 0;
        int nA = LOADB(0, A);
        while (nA) {
            const int nB = LOADB(bb + 1, B);   // prefetch next batch
            PROC(A, nA);
            if (!nB) break;
            nA = LOADB(bb + 2, A);             // prefetch following batch
            PROC(B, nB);
            bb += 2;
        }
    }

    ((float4*)&s_sum[wave][lane * 4])[0] = sum;
    if (lane == 0) s_loss[wave] = lsum;
    __syncthreads();

    const float tot = s_sum[0][tid] + s_sum[1][tid] + s_sum[2][tid] + s_sum[3][tid];
    atomicAdd(&accum[(size_t)c * D + tid], tot);       // chain depth = CPB
    if (tid == 0) {
        const double bl = (double)(s_loss[0] + s_loss[1] + s_loss[2] + s_loss[3]);
        atomicAdd(lossacc, bl);
    }
}

__global__ __launch_bounds__(256) void finalize_kernel(
        const float* __restrict__ accum, const float* __restrict__ centers,
        const int* __restrict__ counts, const double* __restrict__ lossacc,
        int n, float* __restrict__ out) {
    const int c = blockIdx.x;
    const int t = threadIdx.x;
    const int cnt = counts[c];
    const float cs = centers[(size_t)c * D + t];
    const float s = accum[(size_t)c * D + t];
    const float o = (cnt > 0) ? cs + 0.5f * (s / (float)cnt - cs) : cs;  // ALPHA=0.5
    out[1 + (size_t)c * D + t] = o;
    if (c == 0 && t == 0) out[0] = (float)(*lossacc / (double)n * 0.5);
}

extern "C" void kernel_launch(void* const* d_in, const int* in_sizes, int n_in,
                              void* d_out, int out_size, void* d_ws, size_t ws_size,
                              hipStream_t stream) {
    const float* x       = (const float*)d_in[0];
    const int*   lraw    = (const int*)d_in[1];
    const float* centers = (const float*)d_in[2];
    float* out = (float*)d_out;

    const int n = in_sizes[1];            // 262144 rows
    const int C = in_sizes[2] / D;        // 1000 classes

    // workspace layout (byte offsets into 0xAA-poisoned d_ws)
    char* ws = (char*)d_ws;
    int*    counts   = (int*)(ws + 0);        // 1024 ints
    int*    offsets  = (int*)(ws + 4096);     // 1024 ints
    int*    bars     = (int*)(ws + 8192);     // bar0, bar1 (+spare)
    double* lossacc  = (double*)(ws + 8208);  // 8-aligned
    int*    hist_all = (int*)(ws + 16384);    // 64*1024 ints (256 KB)
    int*    rowidx   = (int*)(ws + 524288);   // n ints (1 MB)
    float*  accum    = (float*)(ws + 2097152);// C*D floats (1 MB)

    hipLaunchKernelGGL(init_kernel, dim3(128), dim3(256), 0, stream,
                       accum, counts, bars, lossacc);
    hipLaunchKernelGGL(setup_kernel, dim3(SETUP_BLOCKS), dim3(SETUP_THREADS), 0, stream,
                       lraw, n, counts, offsets, &bars[0], &bars[1], hist_all, rowidx);
    hipLaunchKernelGGL(main_kernel, dim3(C * CPB), dim3(MAIN_THREADS), 0, stream,
                       x, centers, offsets, counts, rowidx, accum, lossacc);
    hipLaunchKernelGGL(finalize_kernel, dim3(C), dim3(256), 0, stream,
                       accum, centers, counts, lossacc, n, out);
}

// Round 4
// 403.021 us; speedup vs baseline: 1.2655x; 1.0452x over previous
//
#include <hip/hip_runtime.h>
#include <math.h>

// CenterLoss on MI355X (gfx950).
// out[0] = mean(||x_i - centers[label_i]||)/2 ; out[1..] = updated centers [1000][256].
//
// 4 launches:
//   init_kernel     : zero accum/counters/barriers/lossacc (ws is 0xAA-poisoned)
//   setup_kernel    : fused hist -> scan -> scatter counting sort (64 co-resident
//                     blocks + software grid barrier, LDS-privatized histogram)
//   main_kernel     : 2 blocks per class, contiguous halves of the sorted row list.
//                     BRANCH-FREE masked batches (invalid rows load s_idx[0] with
//                     weight 0) + explicit 2-deep A/B register pipeline, so the
//                     compiler can keep 16KB/wave of x-gathers in flight. Index
//                     path lives in LDS (lgkmcnt), never touching vmcnt.
//   finalize_kernel : centers update from accum/counts; writes out[0].

#define D 256
#define SETUP_BLOCKS 64
#define SETUP_THREADS 1024
#define U 8                    // rows per batch per wave
#define BROWS 32               // rows per batch per block (4 waves * U)

// ---- software grid barrier (SETUP_BLOCKS co-resident: 64 blocks << 256 CUs) ----
__device__ __forceinline__ void grid_barrier(int* bar) {
    __syncthreads();
    if (threadIdx.x == 0) {
        __threadfence();
        atomicAdd(bar, 1);
        while (__hip_atomic_load(bar, __ATOMIC_ACQUIRE, __HIP_MEMORY_SCOPE_AGENT)
               < SETUP_BLOCKS) {
            __builtin_amdgcn_s_sleep(2);
        }
    }
    __syncthreads();
}

__global__ __launch_bounds__(256) void init_kernel(float* __restrict__ accum,
                                                   int* __restrict__ counts,
                                                   int* __restrict__ bars,
                                                   double* __restrict__ lossacc) {
    float4* a4 = (float4*)accum;                       // 1000*256 floats = 64000 f4
    for (int i = blockIdx.x * 256 + threadIdx.x; i < 64000; i += gridDim.x * 256)
        a4[i] = make_float4(0.f, 0.f, 0.f, 0.f);
    if (blockIdx.x == 0) {
        for (int i = threadIdx.x; i < 1024; i += 256) counts[i] = 0;
        if (threadIdx.x < 3) bars[threadIdx.x] = 0;
        if (threadIdx.x == 0) *lossacc = 0.0;
    }
}

// Fused counting sort (unchanged — verified correct in rounds 2-3).
__global__ __launch_bounds__(SETUP_THREADS) void setup_kernel(
        const int* __restrict__ lraw, int n,
        int* __restrict__ counts, int* __restrict__ offsets,
        int* __restrict__ bar0, int* __restrict__ bar1,
        int* __restrict__ hist_all, int* __restrict__ rowidx) {
    __shared__ int sh[1024];
    __shared__ int s_flag;
    const int tid = threadIdx.x;
    const int b = blockIdx.x;

    if (tid == 0) s_flag = 0;
    sh[tid] = 0;
    __syncthreads();
    if (tid < 512 && 2 * tid + 1 < n) {
        if (lraw[2 * tid + 1]) atomicOr(&s_flag, 1);
    }
    __syncthreads();
    const int f64 = (s_flag == 0) ? 1 : 0;

    for (int i = b * SETUP_THREADS + tid; i < n; i += SETUP_BLOCKS * SETUP_THREADS) {
        const int lbl = f64 ? lraw[2 * (size_t)i] : lraw[i];
        atomicAdd(&sh[lbl], 1);
    }
    __syncthreads();
    const int myh = sh[tid];
    hist_all[b * 1024 + tid] = myh;
    if (myh) atomicAdd(&counts[tid], myh);

    grid_barrier(bar0);

    if (b == 0) {
        const int v = counts[tid];
        sh[tid] = v;
        __syncthreads();
        for (int off = 1; off < 1024; off <<= 1) {
            const int add = (tid >= off) ? sh[tid - off] : 0;
            __syncthreads();
            sh[tid] += add;
            __syncthreads();
        }
        offsets[tid] = sh[tid] - v;
    }

    grid_barrier(bar1);

    int base = offsets[tid];
    for (int pb = 0; pb < b; ++pb) base += hist_all[pb * 1024 + tid];
    __syncthreads();
    sh[tid] = base;
    __syncthreads();
    for (int i = b * SETUP_THREADS + tid; i < n; i += SETUP_BLOCKS * SETUP_THREADS) {
        const int lbl = f64 ? lraw[2 * (size_t)i] : lraw[i];
        const int pos = atomicAdd(&sh[lbl], 1);
        rowidx[pos] = i;
    }
}

// 2 blocks per class; wave w owns rows [batch*32 + w*8, +8) of its segment.
// Branch-free masked batches; explicit 2-deep register pipeline.
__global__ __launch_bounds__(256, 4) void main_kernel(
        const float* __restrict__ x, const float* __restrict__ centers,
        const int* __restrict__ offsets, const int* __restrict__ counts,
        const int* __restrict__ rowidx,
        float* __restrict__ accum, double* __restrict__ lossacc) {
    const int c = blockIdx.x >> 1;
    const int p = blockIdx.x & 1;
    const int tid = threadIdx.x;
    const int wave = tid >> 6;
    const int lane = tid & 63;

    __shared__ int s_idx[256];
    __shared__ float s_sum[4][D];
    __shared__ float s_loss[4];

    const float4 ctr = ((const float4*)(centers + (size_t)c * D))[lane];
    const int start = offsets[c];
    const int cnt = counts[c];
    const int half = (cnt + 1) >> 1;                 // CPB = 2
    const int lo = start + p * half;
    int len = cnt - p * half;
    len = len < 0 ? 0 : (len > half ? half : len);

    float4 sum = make_float4(0.f, 0.f, 0.f, 0.f);
    float lsum = 0.f;

    for (int seg0 = 0; seg0 < len; seg0 += 256) {    // safety outer loop (seg<=256)
        const int seg = min(256, len - seg0);
        __syncthreads();
        if (tid < seg) s_idx[tid] = rowidx[lo + seg0 + tid];
        __syncthreads();

        const int nb = (seg + BROWS - 1) / BROWS;    // batches of 32 rows, >=1

        float4 A[U], B[U];

        auto LOADB = [&](int bb, float4* buf) {
            #pragma unroll
            for (int k = 0; k < U; ++k) {
                const int pos = bb * BROWS + wave * U + k;
                const int safe = (pos < seg) ? pos : 0;    // junk rows re-read s_idx[0]
                const int r = s_idx[safe];                 // LDS: lgkmcnt only
                buf[k] = ((const float4*)(x + (size_t)r * D))[lane];
            }
        };
        auto PROCB = [&](int bb, const float4* buf) {
            #pragma unroll
            for (int k = 0; k < U; ++k) {
                const int pos = bb * BROWS + wave * U + k;
                const float w = (pos < seg) ? 1.f : 0.f;   // mask, no branch
                const float4 v = buf[k];
                sum.x = fmaf(w, v.x, sum.x);
                sum.y = fmaf(w, v.y, sum.y);
                sum.z = fmaf(w, v.z, sum.z);
                sum.w = fmaf(w, v.w, sum.w);
                const float dx = v.x - ctr.x, dy = v.y - ctr.y;
                const float dz = v.z - ctr.z, dw = v.w - ctr.w;
                float sq = w * (dx * dx + dy * dy + dz * dz + dw * dw);
                #pragma unroll
                for (int o = 32; o; o >>= 1) sq += __shfl_xor(sq, o, 64);
                lsum += sqrtf(sq);                         // sqrt(0)=0 for junk
            }
        };

        LOADB(0, A);
        for (int bb = 0; bb < nb; bb += 2) {
            LOADB(bb + 1, B);      // prefetch (masked-safe past end)
            PROCB(bb, A);
            LOADB(bb + 2, A);      // prefetch (masked-safe past end)
            PROCB(bb + 1, B);      // zero-contribution if bb+1 >= nb
        }
    }

    ((float4*)&s_sum[wave][lane * 4])[0] = sum;
    if (lane == 0) s_loss[wave] = lsum;
    __syncthreads();

    const float tot = s_sum[0][tid] + s_sum[1][tid] + s_sum[2][tid] + s_sum[3][tid];
    atomicAdd(&accum[(size_t)c * D + tid], tot);           // chain depth = 2
    if (tid == 0) {
        const double bl = (double)(s_loss[0] + s_loss[1] + s_loss[2] + s_loss[3]);
        atomicAdd(lossacc, bl);
    }
}

__global__ __launch_bounds__(256) void finalize_kernel(
        const float* __restrict__ accum, const float* __restrict__ centers,
        const int* __restrict__ counts, const double* __restrict__ lossacc,
        int n, float* __restrict__ out) {
    const int c = blockIdx.x;
    const int t = threadIdx.x;
    const int cnt = counts[c];
    const float cs = centers[(size_t)c * D + t];
    const float s = accum[(size_t)c * D + t];
    const float o = (cnt > 0) ? cs + 0.5f * (s / (float)cnt - cs) : cs;  // ALPHA=0.5
    out[1 + (size_t)c * D + t] = o;
    if (c == 0 && t == 0) out[0] = (float)(*lossacc / (double)n * 0.5);
}

extern "C" void kernel_launch(void* const* d_in, const int* in_sizes, int n_in,
                              void* d_out, int out_size, void* d_ws, size_t ws_size,
                              hipStream_t stream) {
    const float* x       = (const float*)d_in[0];
    const int*   lraw    = (const int*)d_in[1];
    const float* centers = (const float*)d_in[2];
    float* out = (float*)d_out;

    const int n = in_sizes[1];            // 262144 rows
    const int C = in_sizes[2] / D;        // 1000 classes

    // workspace layout (byte offsets into 0xAA-poisoned d_ws)
    char* ws = (char*)d_ws;
    int*    counts   = (int*)(ws + 0);        // 1024 ints
    int*    offsets  = (int*)(ws + 4096);     // 1024 ints
    int*    bars     = (int*)(ws + 8192);     // bar0, bar1 (+spare)
    double* lossacc  = (double*)(ws + 8208);  // 8-aligned
    int*    hist_all = (int*)(ws + 16384);    // 64*1024 ints (256 KB)
    int*    rowidx   = (int*)(ws + 524288);   // n ints (1 MB)
    float*  accum    = (float*)(ws + 2097152);// C*D floats (1 MB)

    hipLaunchKernelGGL(init_kernel, dim3(128), dim3(256), 0, stream,
                       accum, counts, bars, lossacc);
    hipLaunchKernelGGL(setup_kernel, dim3(SETUP_BLOCKS), dim3(SETUP_THREADS), 0, stream,
                       lraw, n, counts, offsets, &bars[0], &bars[1], hist_all, rowidx);
    hipLaunchKernelGGL(main_kernel, dim3(C * 2), dim3(256), 0, stream,
                       x, centers, offsets, counts, rowidx, accum, lossacc);
    hipLaunchKernelGGL(finalize_kernel, dim3(C), dim3(256), 0, stream,
                       accum, centers, counts, lossacc, n, out);
}

// Round 5
// 402.194 us; speedup vs baseline: 1.2681x; 1.0021x over previous
//
#include <hip/hip_runtime.h>
#include <math.h>

// CenterLoss on MI355X (gfx950).
// out[0] = mean(||x_i - centers[label_i]||)/2 ; out[1..] = updated centers [1000][256].
//
// main_kernel v5: row gather via __builtin_amdgcn_global_load_lds (width=16:
// ONE instruction stages a whole 1KB x-row to LDS) with a per-wave 10-slot ring
// and MANUAL counted s_waitcnt vmcnt(7..0) -- 8 rows (8KB) permanently in
// flight per wave, independent of compiler scheduling. 12 waves/CU -> ~96KB
// in flight per CU >> Little's-law minimum (~9KB @ 900cy HBM latency).

#define D 256
#define SETUP_BLOCKS 64
#define SETUP_THREADS 1024
#define CH 256          // rows per s_idx chunk
#define SLOTS 10        // LDS row slots per wave (ring)
#define INFLIGHT 8      // outstanding global_load_lds per wave

#define VMWAIT(n) asm volatile("s_waitcnt vmcnt(" #n ")" ::: "memory")

// ---- software grid barrier (SETUP_BLOCKS co-resident: 64 blocks << 256 CUs) ----
__device__ __forceinline__ void grid_barrier(int* bar) {
    __syncthreads();
    if (threadIdx.x == 0) {
        __threadfence();
        atomicAdd(bar, 1);
        while (__hip_atomic_load(bar, __ATOMIC_ACQUIRE, __HIP_MEMORY_SCOPE_AGENT)
               < SETUP_BLOCKS) {
            __builtin_amdgcn_s_sleep(2);
        }
    }
    __syncthreads();
}

__global__ __launch_bounds__(256) void init_kernel(float* __restrict__ accum,
                                                   int* __restrict__ counts,
                                                   int* __restrict__ bars,
                                                   double* __restrict__ lossacc) {
    float4* a4 = (float4*)accum;                       // 1000*256 floats = 64000 f4
    for (int i = blockIdx.x * 256 + threadIdx.x; i < 64000; i += gridDim.x * 256)
        a4[i] = make_float4(0.f, 0.f, 0.f, 0.f);
    if (blockIdx.x == 0) {
        for (int i = threadIdx.x; i < 1024; i += 256) counts[i] = 0;
        if (threadIdx.x < 3) bars[threadIdx.x] = 0;
        if (threadIdx.x == 0) *lossacc = 0.0;
    }
}

// Fused counting sort (unchanged -- verified correct rounds 2-4).
__global__ __launch_bounds__(SETUP_THREADS) void setup_kernel(
        const int* __restrict__ lraw, int n,
        int* __restrict__ counts, int* __restrict__ offsets,
        int* __restrict__ bar0, int* __restrict__ bar1,
        int* __restrict__ hist_all, int* __restrict__ rowidx) {
    __shared__ int sh[1024];
    __shared__ int s_flag;
    const int tid = threadIdx.x;
    const int b = blockIdx.x;

    if (tid == 0) s_flag = 0;
    sh[tid] = 0;
    __syncthreads();
    if (tid < 512 && 2 * tid + 1 < n) {
        if (lraw[2 * tid + 1]) atomicOr(&s_flag, 1);
    }
    __syncthreads();
    const int f64 = (s_flag == 0) ? 1 : 0;

    for (int i = b * SETUP_THREADS + tid; i < n; i += SETUP_BLOCKS * SETUP_THREADS) {
        const int lbl = f64 ? lraw[2 * (size_t)i] : lraw[i];
        atomicAdd(&sh[lbl], 1);
    }
    __syncthreads();
    const int myh = sh[tid];
    hist_all[b * 1024 + tid] = myh;
    if (myh) atomicAdd(&counts[tid], myh);

    grid_barrier(bar0);

    if (b == 0) {
        const int v = counts[tid];
        sh[tid] = v;
        __syncthreads();
        for (int off = 1; off < 1024; off <<= 1) {
            const int add = (tid >= off) ? sh[tid - off] : 0;
            __syncthreads();
            sh[tid] += add;
            __syncthreads();
        }
        offsets[tid] = sh[tid] - v;
    }

    grid_barrier(bar1);

    int base = offsets[tid];
    for (int pb = 0; pb < b; ++pb) base += hist_all[pb * 1024 + tid];
    __syncthreads();
    sh[tid] = base;
    __syncthreads();
    for (int i = b * SETUP_THREADS + tid; i < n; i += SETUP_BLOCKS * SETUP_THREADS) {
        const int lbl = f64 ? lraw[2 * (size_t)i] : lraw[i];
        const int pos = atomicAdd(&sh[lbl], 1);
        rowidx[pos] = i;
    }
}

// 2 blocks per class (contiguous halves); 4 waves; wave w owns rows w,w+4,w+8,...
// of each 256-row chunk. LDS ring + manual vmcnt keeps 8 rows/wave in flight.
__global__ __launch_bounds__(256, 4) void main_kernel(
        const float* __restrict__ x, const float* __restrict__ centers,
        const int* __restrict__ offsets, const int* __restrict__ counts,
        const int* __restrict__ rowidx,
        float* __restrict__ accum, double* __restrict__ lossacc) {
    const int c = blockIdx.x >> 1;
    const int p = blockIdx.x & 1;
    const int tid = threadIdx.x;
    const int wave = tid >> 6;
    const int lane = tid & 63;

    __shared__ int   s_idx[CH];
    __shared__ float s_stage[4][SLOTS][D];     // 40 KB: per-wave private ring
    __shared__ float s_sum[4][D];
    __shared__ float s_loss[4];

    const float4 ctr = ((const float4*)(centers + (size_t)c * D))[lane];
    const int start = offsets[c];
    const int cnt = counts[c];
    const int half = (cnt + 1) >> 1;
    const int lo = start + p * half;
    int len = cnt - p * half;
    len = len < 0 ? 0 : (len > half ? half : len);

    float4 sum = make_float4(0.f, 0.f, 0.f, 0.f);
    float lsum = 0.f;

    float* const st = &s_stage[wave][0][0];

    for (int cb = 0; cb < len; cb += CH) {       // block-uniform trip count
        const int seg = min(CH, len - cb);
        __syncthreads();                          // drains vmcnt/lgkmcnt
        if (tid < seg) s_idx[tid] = rowidx[lo + cb + tid];
        __syncthreads();

        const int jtot = (seg + 3) >> 2;          // max rows/wave (uniform)

        auto ISSUE = [&](int j) {                 // stage row (wave,j) -> slot j%SLOTS
            const int pos  = wave + 4 * j;
            const int safe = (pos < seg) ? pos : (seg - 1);
            const int r    = s_idx[safe];                       // LDS (lgkm)
            const float* src = x + (size_t)r * D + lane * 4;    // per-lane 16B
            float* dst = st + (j % SLOTS) * D;                  // wave-uniform base
            __builtin_amdgcn_global_load_lds(
                (const __attribute__((address_space(1))) void*)src,
                (__attribute__((address_space(3))) void*)dst, 16, 0, 0);
        };
        auto PROCR = [&](int j) {                 // consume row (wave,j), masked
            const int jj  = (j < 0) ? 0 : j;
            const int pos = wave + 4 * jj;
            const float w = (j >= 0 && pos < seg) ? 1.f : 0.f;
            const float4 v = ((const float4*)(st + (jj % SLOTS) * D))[lane];
            sum.x = fmaf(w, v.x, sum.x);
            sum.y = fmaf(w, v.y, sum.y);
            sum.z = fmaf(w, v.z, sum.z);
            sum.w = fmaf(w, v.w, sum.w);
            const float dx = v.x - ctr.x, dy = v.y - ctr.y;
            const float dz = v.z - ctr.z, dw = v.w - ctr.w;
            float sq = w * (dx * dx + dy * dy + dz * dz + dw * dw);
            #pragma unroll
            for (int o = 32; o; o >>= 1) sq += __shfl_xor(sq, o, 64);
            lsum += sqrtf(sq);                    // sqrt(0)=0 for masked rows
        };

        #pragma unroll
        for (int j = 0; j < INFLIGHT; ++j)        // prologue: exactly 8 issues
            ISSUE(j < jtot ? j : jtot - 1);       // (duplicates benign)

        for (int j = INFLIGHT; j < jtot; ++j) {   // steady state: 8 in flight
            VMWAIT(7);                            // row j-8 has landed in LDS
            PROCR(j - INFLIGHT);
            ISSUE(j);
        }
        // epilogue: drain the last 8 (masked if jtot < 8)
        VMWAIT(7); PROCR(jtot - 8);
        VMWAIT(6); PROCR(jtot - 7);
        VMWAIT(5); PROCR(jtot - 6);
        VMWAIT(4); PROCR(jtot - 5);
        VMWAIT(3); PROCR(jtot - 4);
        VMWAIT(2); PROCR(jtot - 3);
        VMWAIT(1); PROCR(jtot - 2);
        VMWAIT(0); PROCR(jtot - 1);
    }

    ((float4*)&s_sum[wave][lane * 4])[0] = sum;
    if (lane == 0) s_loss[wave] = lsum;
    __syncthreads();

    const float tot = s_sum[0][tid] + s_sum[1][tid] + s_sum[2][tid] + s_sum[3][tid];
    atomicAdd(&accum[(size_t)c * D + tid], tot);           // chain depth = 2
    if (tid == 0) {
        const double bl = (double)(s_loss[0] + s_loss[1] + s_loss[2] + s_loss[3]);
        atomicAdd(lossacc, bl);
    }
}

__global__ __launch_bounds__(256) void finalize_kernel(
        const float* __restrict__ accum, const float* __restrict__ centers,
        const int* __restrict__ counts, const double* __restrict__ lossacc,
        int n, float* __restrict__ out) {
    const int c = blockIdx.x;
    const int t = threadIdx.x;
    const int cnt = counts[c];
    const float cs = centers[(size_t)c * D + t];
    const float s = accum[(size_t)c * D + t];
    const float o = (cnt > 0) ? cs + 0.5f * (s / (float)cnt - cs) : cs;  // ALPHA=0.5
    out[1 + (size_t)c * D + t] = o;
    if (c == 0 && t == 0) out[0] = (float)(*lossacc / (double)n * 0.5);
}

extern "C" void kernel_launch(void* const* d_in, const int* in_sizes, int n_in,
                              void* d_out, int out_size, void* d_ws, size_t ws_size,
                              hipStream_t stream) {
    const float* x       = (const float*)d_in[0];
    const int*   lraw    = (const int*)d_in[1];
    const float* centers = (const float*)d_in[2];
    float* out = (float*)d_out;

    const int n = in_sizes[1];            // 262144 rows
    const int C = in_sizes[2] / D;        // 1000 classes

    // workspace layout (byte offsets into 0xAA-poisoned d_ws)
    char* ws = (char*)d_ws;
    int*    counts   = (int*)(ws + 0);        // 1024 ints
    int*    offsets  = (int*)(ws + 4096);     // 1024 ints
    int*    bars     = (int*)(ws + 8192);     // bar0, bar1 (+spare)
    double* lossacc  = (double*)(ws + 8208);  // 8-aligned
    int*    hist_all = (int*)(ws + 16384);    // 64*1024 ints (256 KB)
    int*    rowidx   = (int*)(ws + 524288);   // n ints (1 MB)
    float*  accum    = (float*)(ws + 2097152);// C*D floats (1 MB)

    hipLaunchKernelGGL(init_kernel, dim3(128), dim3(256), 0, stream,
                       accum, counts, bars, lossacc);
    hipLaunchKernelGGL(setup_kernel, dim3(SETUP_BLOCKS), dim3(SETUP_THREADS), 0, stream,
                       lraw, n, counts, offsets, &bars[0], &bars[1], hist_all, rowidx);
    hipLaunchKernelGGL(main_kernel, dim3(C * 2), dim3(256), 0, stream,
                       x, centers, offsets, counts, rowidx, accum, lossacc);
    hipLaunchKernelGGL(finalize_kernel, dim3(C), dim3(256), 0, stream,
                       accum, centers, counts, lossacc, n, out);
}